// Round 3
// baseline (125.076 us; speedup 1.0000x reference)
//
#include <hip/hip_runtime.h>
#include <math.h>

// PinSAGE fused pipeline, bf16-MFMA, operand-swapped (C^T) edition.
// Constants fixed by the reference: D=U=E=128, T=20. N, V from in_sizes.
//
// GEMM structure (per 16x16x32 MFMA): A-operand = W-fragment, B-operand =
// row-fragment  =>  lane l holds C[row = 16nt+ (l&15)][cols 16mt+4*(l>>4)+i],
// i.e. 4 CONSECUTIVE columns of one row per f32x4 accumulator:
//   - A (data rows) loads go global->register directly (16/32 B per lane)
//   - C stores go register->global directly (uint2 bf16 / f32x4)
//   - LDS holds only the 32 KB W tile (XOR-swizzled, conflict-free reads)
//
// Pipeline:
//   0) prep:  WqT/WnT/WwT/WgT = bf16 transpose of weights (WT[n][k])
//   1) H    = relu(table @ Wn + bn)            -> bf16 [V][128]
//   2) nodeh= relu(table[node_ids] @ Wq + bq)  -> bf16 nh[:,0:128]
//   3) agg  = sum_t alpha * H[neigh]           -> bf16 nh[:,128:256]
//   4) emb  = relu(nh @ Ww + bw)               -> bf16 embb + fp32 sumsq
//   5) scale= 1/sqrt(sum sumsq)
//   6) out  = relu(scale*(emb @ Wg) + bg)      -> fp32 d_out

using f32x4  = __attribute__((ext_vector_type(4))) float;
using short8 = __attribute__((ext_vector_type(8))) short;   // 8 bf16 (4 VGPRs)

__device__ __forceinline__ ushort f2bf(float f) {
    uint u = __float_as_uint(f);
    return (ushort)((u + 0x7fffu + ((u >> 16) & 1u)) >> 16);   // RNE
}
__device__ __forceinline__ float bf2f(ushort h) {
    return __uint_as_float((uint)h << 16);
}
__device__ __forceinline__ uint pk2(float lo, float hi) {
    return (uint)f2bf(lo) | ((uint)f2bf(hi) << 16);
}
__device__ __forceinline__ short8 pack8(f32x4 a, f32x4 b) {
    uint u0 = pk2(a[0], a[1]), u1 = pk2(a[2], a[3]);
    uint u2 = pk2(b[0], b[1]), u3 = pk2(b[2], b[3]);
    uint4 r; r.x = u0; r.y = u1; r.z = u2; r.w = u3;
    union { uint4 u; short8 s; } cv; cv.u = r; return cv.s;
}

// ---------------------------------------------------------------------------
// Weight prep: WT[n][K] (bf16) = W[k][n].  81920 elements over 4 mats.
// ---------------------------------------------------------------------------
__global__ __launch_bounds__(256)
void prep_weights(const float* __restrict__ Wq, const float* __restrict__ Wn,
                  const float* __restrict__ Ww, const float* __restrict__ Wg,
                  ushort* __restrict__ WqT, ushort* __restrict__ WnT,
                  ushort* __restrict__ WwT, ushort* __restrict__ WgT)
{
    int idx = blockIdx.x * 256 + threadIdx.x;   // grid = 320 blocks -> 81920
    const float* W; ushort* WT; int K; int j = idx;
    if (j < 16384)      { W = Wq; WT = WqT; K = 128; }
    else if (j < 32768) { W = Wn; WT = WnT; K = 128; j -= 16384; }
    else if (j < 65536) { W = Ww; WT = WwT; K = 256; j -= 32768; }
    else                { W = Wg; WT = WgT; K = 128; j -= 65536; }
    int n = j & 127, k = j >> 7;                // W row-major [K][128]: j = k*128+n
    WT[(size_t)n * K + k] = f2bf(W[j]);
}

// ---------------------------------------------------------------------------
// Swapped-operand MFMA GEMM. 128 rows/block, 256 thr = 4 waves,
// wave w owns rows 32w..32w+31 (nt=0/1), all 128 output cols (mt=0..7).
// ---------------------------------------------------------------------------
template<int KTOT, bool GATHER, bool AFP32, bool SUMSQ, bool SCALE, bool OUTFP32>
__global__ __launch_bounds__(256, 2)
void mfma_gemm(const void* __restrict__ Av, int lda,
               const int* __restrict__ gidx,
               const ushort* __restrict__ WT,   // [128][KTOT] bf16 pre-transposed
               const float* __restrict__ bias,
               void* __restrict__ outv, int ldo, int M,
               float* __restrict__ partials,
               const float* __restrict__ scale_ptr)
{
    __shared__ __align__(16) ushort Blds[128 * 128];   // 32 KB W tile, swizzled
    __shared__ float red[256];

    const int tid = threadIdx.x;
    const int w = tid >> 6, l = tid & 63;
    const int l16 = l & 15, lh = l >> 4;
    const int brow = blockIdx.x * 128;

    const int row0 = brow + 32 * w + l16;      // nt=0 row
    const int row1 = row0 + 16;                // nt=1 row
    int g0 = (row0 < M) ? row0 : (M - 1);
    int g1 = (row1 < M) ? row1 : (M - 1);
    if (GATHER) { g0 = gidx[g0]; g1 = gidx[g1]; }

    f32x4 acc[2][8];
#pragma unroll
    for (int nt = 0; nt < 2; ++nt)
#pragma unroll
        for (int mt = 0; mt < 8; ++mt)
#pragma unroll
            for (int i = 0; i < 4; ++i) acc[nt][mt][i] = 0.f;

    for (int kc = 0; kc < KTOT / 128; ++kc) {
        const int kbase = kc * 128;

        // ---- issue A fragment loads (global -> regs), independent of LDS ----
        short8 a[2][4];
        f32x4 t[2][8];
        if (AFP32) {
            const float* A = (const float*)Av;
#pragma unroll
            for (int nt = 0; nt < 2; ++nt) {
                const float* rp = A + (size_t)(nt ? g1 : g0) * lda + kbase + 8 * lh;
#pragma unroll
                for (int ks = 0; ks < 4; ++ks) {
                    t[nt][2 * ks]     = *reinterpret_cast<const f32x4*>(rp + 32 * ks);
                    t[nt][2 * ks + 1] = *reinterpret_cast<const f32x4*>(rp + 32 * ks + 4);
                }
            }
        } else {
            const ushort* A = (const ushort*)Av;
#pragma unroll
            for (int nt = 0; nt < 2; ++nt) {
                const ushort* rp = A + (size_t)(nt ? g1 : g0) * lda + kbase + 8 * lh;
#pragma unroll
                for (int ks = 0; ks < 4; ++ks)
                    a[nt][ks] = *reinterpret_cast<const short8*>(rp + 32 * ks);
            }
        }

        // ---- stage W chunk into LDS (swizzled): rows n, k in [kbase,+128) ----
        if (kc > 0) __syncthreads();           // prior MFMA readers done
#pragma unroll
        for (int it = 0; it < 8; ++it) {
            int idx = it * 256 + tid;          // 0..2047
            int n = idx >> 4, o = idx & 15;
            uint4 v = *reinterpret_cast<const uint4*>(&WT[(size_t)n * KTOT + kbase + 8 * o]);
            *reinterpret_cast<uint4*>(
                (char*)Blds + n * 256 + ((16 * o) ^ ((n & 7) << 4))) = v;
        }
        __syncthreads();

        if (AFP32) {
#pragma unroll
            for (int nt = 0; nt < 2; ++nt)
#pragma unroll
                for (int ks = 0; ks < 4; ++ks)
                    a[nt][ks] = pack8(t[nt][2 * ks], t[nt][2 * ks + 1]);
        }

        // ---- MFMA: 4 k-steps x 8 col-tiles x 2 row-tiles ----
#pragma unroll
        for (int ks = 0; ks < 4; ++ks) {
#pragma unroll
            for (int mt = 0; mt < 8; ++mt) {
                short8 wf = *reinterpret_cast<const short8*>(
                    (char*)Blds + (16 * mt + l16) * 256 +
                    ((64 * ks + 16 * lh) ^ ((l16 & 7) << 4)));
                acc[0][mt] = __builtin_amdgcn_mfma_f32_16x16x32_bf16(wf, a[0][ks], acc[0][mt], 0, 0, 0);
                acc[1][mt] = __builtin_amdgcn_mfma_f32_16x16x32_bf16(wf, a[1][ks], acc[1][mt], 0, 0, 0);
            }
        }
    }

    // ---- epilogue: bias+scale+relu, direct global store, optional sumsq ----
    const float scale = SCALE ? scale_ptr[0] : 1.0f;
    float ssq = 0.f;
#pragma unroll
    for (int nt = 0; nt < 2; ++nt) {
        const int row = nt ? row1 : row0;
        const bool ok = row < M;
#pragma unroll
        for (int mt = 0; mt < 8; ++mt) {
            const f32x4 bv = *reinterpret_cast<const f32x4*>(&bias[16 * mt + 4 * lh]);
            f32x4 v;
#pragma unroll
            for (int i = 0; i < 4; ++i)
                v[i] = fmaxf(fmaf(acc[nt][mt][i], scale, bv[i]), 0.f);
            if (SUMSQ && ok)
                ssq += v[0] * v[0] + v[1] * v[1] + v[2] * v[2] + v[3] * v[3];
            if (OUTFP32) {
                if (ok)
                    *reinterpret_cast<f32x4*>(
                        &((float*)outv)[(size_t)row * ldo + 16 * mt + 4 * lh]) = v;
            } else {
                uint2 p; p.x = pk2(v[0], v[1]); p.y = pk2(v[2], v[3]);
                if (ok)
                    *reinterpret_cast<uint2*>(
                        &((ushort*)outv)[(size_t)row * ldo + 16 * mt + 4 * lh]) = p;
            }
        }
    }

    if (SUMSQ) {
        red[tid] = ssq;
        __syncthreads();
        for (int st = 128; st > 0; st >>= 1) {
            if (tid < st) red[tid] += red[tid + st];
            __syncthreads();
        }
        if (tid == 0) partials[blockIdx.x] = red[0];
    }
}

// ---------------------------------------------------------------------------
// agg[n][:] = sum_t alpha[n,t] * H[neigh_ids[n,t]][:]   (H bf16, out bf16)
// 256 thr = 16 rows x 16 lanes of bf16x8 (16 B each).
// ---------------------------------------------------------------------------
__global__ __launch_bounds__(256)
void agg_bf16(const ushort* __restrict__ H,
              const int* __restrict__ nids,
              const float* __restrict__ alpha,
              ushort* __restrict__ outb,     // points at nh + 128, row stride 256
              int N)
{
    const int n   = blockIdx.x * 16 + (threadIdx.x >> 4);
    const int l16 = threadIdx.x & 15;
    if (n >= N) return;

    const int*   idp = &nids[n * 20];
    const float* alp = &alpha[n * 20];
    float a[8];
#pragma unroll
    for (int j = 0; j < 8; ++j) a[j] = 0.f;

#pragma unroll
    for (int t = 0; t < 20; ++t) {
        const int   id = idp[t];
        const float al = alp[t];
        uint4 h = *reinterpret_cast<const uint4*>(&H[(size_t)id * 128 + 8 * l16]);
        a[0] = fmaf(al, bf2f((ushort)(h.x & 0xffff)), a[0]);
        a[1] = fmaf(al, bf2f((ushort)(h.x >> 16)),    a[1]);
        a[2] = fmaf(al, bf2f((ushort)(h.y & 0xffff)), a[2]);
        a[3] = fmaf(al, bf2f((ushort)(h.y >> 16)),    a[3]);
        a[4] = fmaf(al, bf2f((ushort)(h.z & 0xffff)), a[4]);
        a[5] = fmaf(al, bf2f((ushort)(h.z >> 16)),    a[5]);
        a[6] = fmaf(al, bf2f((ushort)(h.w & 0xffff)), a[6]);
        a[7] = fmaf(al, bf2f((ushort)(h.w >> 16)),    a[7]);
    }
    uint4 p;
    p.x = pk2(a[0], a[1]);
    p.y = pk2(a[2], a[3]);
    p.z = pk2(a[4], a[5]);
    p.w = pk2(a[6], a[7]);
    *reinterpret_cast<uint4*>(&outb[(size_t)n * 256 + 8 * l16]) = p;
}

// ---------------------------------------------------------------------------
__global__ void reduce_norm(const float* __restrict__ partials, int n,
                            float* __restrict__ scale)
{
    __shared__ float red[256];
    float s = 0.f;
    for (int i = threadIdx.x; i < n; i += 256) s += partials[i];
    red[threadIdx.x] = s;
    __syncthreads();
    for (int st = 128; st > 0; st >>= 1) {
        if (threadIdx.x < st) red[threadIdx.x] += red[threadIdx.x + st];
        __syncthreads();
    }
    if (threadIdx.x == 0) scale[0] = 1.0f / sqrtf(red[0]);
}

// ---------------------------------------------------------------------------
extern "C" void kernel_launch(void* const* d_in, const int* in_sizes, int n_in,
                              void* d_out, int out_size, void* d_ws, size_t ws_size,
                              hipStream_t stream)
{
    const int*   node_ids  = (const int*)  d_in[0];
    const int*   neigh_ids = (const int*)  d_in[1];
    const float* alpha     = (const float*)d_in[2];
    const float* table     = (const float*)d_in[3];
    const float* Wq        = (const float*)d_in[4];
    const float* bq        = (const float*)d_in[5];
    const float* Wn        = (const float*)d_in[6];
    const float* bn        = (const float*)d_in[7];
    const float* Ww        = (const float*)d_in[8];
    const float* bw        = (const float*)d_in[9];
    const float* Wg        = (const float*)d_in[10];
    const float* bg        = (const float*)d_in[11];

    const int N = in_sizes[0];            // 50000
    const int V = in_sizes[3] / 128;      // 200000
    float* out = (float*)d_out;

    // workspace layout (all bf16 except partials/scale)
    ushort* H    = (ushort*)d_ws;                 // [V][128]
    ushort* nh   = H    + (size_t)V * 128;        // [N][256] = [node_h | agg]
    ushort* embb = nh   + (size_t)N * 256;        // [N][128]
    ushort* WqT  = embb + (size_t)N * 128;        // [128][128]
    ushort* WnT  = WqT  + 16384;                  // [128][128]
    ushort* WwT  = WnT  + 16384;                  // [128][256]
    ushort* WgT  = WwT  + 32768;                  // [128][128]
    float*  partials = (float*)(WgT + 16384);     // 512
    float*  scale    = partials + 512;

    const size_t need = (size_t)((char*)(scale + 16) - (char*)d_ws);
    if (ws_size < need) return;   // should not happen

    const int nblkN = (N + 127) / 128;
    const int nblkV = (V + 127) / 128;

    // 0) weights -> bf16 transposed
    prep_weights<<<320, 256, 0, stream>>>(Wq, Wn, Ww, Wg, WqT, WnT, WwT, WgT);
    // 1) H = relu(table @ Wn + bn) -> bf16
    mfma_gemm<128, false, true, false, false, false><<<nblkV, 256, 0, stream>>>(
        table, 128, nullptr, WnT, bn, H, 128, V, nullptr, nullptr);
    // 2) node_h = relu(table[node_ids] @ Wq + bq) -> nh[:, 0:128]
    mfma_gemm<128, true, true, false, false, false><<<nblkN, 256, 0, stream>>>(
        table, 128, node_ids, WqT, bq, nh, 256, N, nullptr, nullptr);
    // 3) agg -> nh[:, 128:256]
    agg_bf16<<<(N + 15) / 16, 256, 0, stream>>>(H, neigh_ids, alpha, nh + 128, N);
    // 4) emb = relu(nh @ Ww + bw) -> bf16 embb, + fp32 sumsq partials
    mfma_gemm<256, false, false, true, false, false><<<nblkN, 256, 0, stream>>>(
        nh, 256, nullptr, WwT, bw, embb, 128, N, partials, nullptr);
    // 5) scale = 1/||emb||_F
    reduce_norm<<<1, 256, 0, stream>>>(partials, nblkN, scale);
    // 6) out = relu(scale*(emb @ Wg) + bg) -> fp32 d_out
    mfma_gemm<128, false, false, false, true, true><<<nblkN, 256, 0, stream>>>(
        embb, 128, nullptr, WgT, bg, out, 128, N, nullptr, scale);
}